// Round 7
// baseline (373.235 us; speedup 1.0000x reference)
//
#include <hip/hip_runtime.h>

#define NN 100000
#define NE 1600000
#define DD 64
#define PAD 32                             // counters 1 per 128B line
#define NOCT 12500                         // NN / 8 nodes-per-wave
#define SCAN_BS 256
#define NBLK ((NN + SCAN_BS - 1) / SCAN_BS)   // 391

// ---------------- zero ----------------
__global__ void zero_kernel(int* __restrict__ p, int n) {
  int i = blockIdx.x * blockDim.x + threadIdx.x;
  int stride = gridDim.x * blockDim.x;
  for (; i < n; i += stride) p[i] = 0;
}

// ---------------- degree histogram + rank record, padded + pipelined --------
// Each thread handles 4 int4 edge groups: load 4 dst quads, issue all 16
// returning atomics (padded counters, one per 128B line), then store the 4
// rank quads. 16 atomic instrs in flight per wave instead of 4.
__global__ void hist_kernel(const int* __restrict__ dst, int* __restrict__ degp,
                            int* __restrict__ rank) {
  const int NQ = NE / 4;                   // 400000
  int t = blockIdx.x * 256 + threadIdx.x;
  int nt = gridDim.x * 256;                // 100096
  bool p0 = t < NQ, p1 = t + nt < NQ, p2 = t + 2 * nt < NQ, p3 = t + 3 * nt < NQ;
  int4 d0, d1, d2, d3;
  if (p0) d0 = reinterpret_cast<const int4*>(dst)[t];
  if (p1) d1 = reinterpret_cast<const int4*>(dst)[t + nt];
  if (p2) d2 = reinterpret_cast<const int4*>(dst)[t + 2 * nt];
  if (p3) d3 = reinterpret_cast<const int4*>(dst)[t + 3 * nt];
  int4 r0, r1, r2, r3;
  if (p0) {
    r0.x = atomicAdd(&degp[d0.x * PAD], 1);
    r0.y = atomicAdd(&degp[d0.y * PAD], 1);
    r0.z = atomicAdd(&degp[d0.z * PAD], 1);
    r0.w = atomicAdd(&degp[d0.w * PAD], 1);
  }
  if (p1) {
    r1.x = atomicAdd(&degp[d1.x * PAD], 1);
    r1.y = atomicAdd(&degp[d1.y * PAD], 1);
    r1.z = atomicAdd(&degp[d1.z * PAD], 1);
    r1.w = atomicAdd(&degp[d1.w * PAD], 1);
  }
  if (p2) {
    r2.x = atomicAdd(&degp[d2.x * PAD], 1);
    r2.y = atomicAdd(&degp[d2.y * PAD], 1);
    r2.z = atomicAdd(&degp[d2.z * PAD], 1);
    r2.w = atomicAdd(&degp[d2.w * PAD], 1);
  }
  if (p3) {
    r3.x = atomicAdd(&degp[d3.x * PAD], 1);
    r3.y = atomicAdd(&degp[d3.y * PAD], 1);
    r3.z = atomicAdd(&degp[d3.z * PAD], 1);
    r3.w = atomicAdd(&degp[d3.w * PAD], 1);
  }
  if (p0) reinterpret_cast<int4*>(rank)[t] = r0;
  if (p1) reinterpret_cast<int4*>(rank)[t + nt] = r1;
  if (p2) reinterpret_cast<int4*>(rank)[t + 2 * nt] = r2;
  if (p3) reinterpret_cast<int4*>(rank)[t + 3 * nt] = r3;
}

// ---------------- scan stage 1 (reads padded degp, emits compact degc) ------
__global__ void scan1_kernel(const int* __restrict__ degp, int* __restrict__ degc,
                             int* __restrict__ off, int* __restrict__ bsum) {
  __shared__ int wsum[4];
  int i = blockIdx.x * SCAN_BS + threadIdx.x;
  int lane = threadIdx.x & 63, g = threadIdx.x >> 6;
  int v = (i < NN) ? degp[i * PAD] : 0;
  if (i < NN) degc[i] = v;
  int incl = v;
  #pragma unroll
  for (int o = 1; o < 64; o <<= 1) {
    int t = __shfl_up(incl, o, 64);
    if (lane >= o) incl += t;
  }
  if (lane == 63) wsum[g] = incl;
  __syncthreads();
  int prefix = 0;
  for (int w = 0; w < g; ++w) prefix += wsum[w];
  if (i < NN) off[i] = prefix + incl - v;
  if (threadIdx.x == SCAN_BS - 1) bsum[blockIdx.x] = prefix + incl;
}

// ---------------- scan stage 2 ----------------
__global__ void scan2_kernel(int* __restrict__ bsum) {
  __shared__ int tmp[512];
  int i = threadIdx.x;
  int v = (i < NBLK) ? bsum[i] : 0;
  tmp[i] = v;
  __syncthreads();
  for (int o = 1; o < 512; o <<= 1) {
    int t = (i >= o) ? tmp[i - o] : 0;
    __syncthreads();
    tmp[i] += t;
    __syncthreads();
  }
  if (i < NBLK) bsum[i] = tmp[i] - v;
}

// ---------------- scan stage 3 ----------------
__global__ void scan3_kernel(int* __restrict__ off, const int* __restrict__ bsum) {
  int i = blockIdx.x * SCAN_BS + threadIdx.x;
  if (i < NN) off[i] += bsum[blockIdx.x];
}

// ---------------- CSR fill: NO atomics (uses precomputed rank) ----------------
__global__ void fill_kernel(const int* __restrict__ src, const int* __restrict__ dst,
                            const int* __restrict__ off, const int* __restrict__ rank,
                            int* __restrict__ adj) {
  int e4 = blockIdx.x * 256 + threadIdx.x;
  if (e4 >= NE / 4) return;
  int4 d = reinterpret_cast<const int4*>(dst)[e4];
  int4 s = reinterpret_cast<const int4*>(src)[e4];
  int4 r = reinterpret_cast<const int4*>(rank)[e4];
  adj[off[d.x] + r.x] = s.x;
  adj[off[d.y] + r.y] = s.y;
  adj[off[d.z] + r.z] = s.z;
  adj[off[d.w] + r.w] = s.w;
}

// ---------------- gather-mean: prop[n] = mean of x[neighbors] --------------
__launch_bounds__(256)
__global__ void gather_kernel(const float* __restrict__ x,
                              const int* __restrict__ off,
                              const int* __restrict__ deg,
                              const int* __restrict__ adj,
                              float* __restrict__ prop) {
  int wid = (blockIdx.x * 256 + threadIdx.x) >> 6;
  int nwaves = (gridDim.x * 256) >> 6;
  int j = threadIdx.x & 63;
  for (int n = wid; n < NN; n += nwaves) {
    int start = __builtin_amdgcn_readfirstlane(off[n]);
    int d     = __builtin_amdgcn_readfirstlane(deg[n]);
    float a0 = 0.f, a1 = 0.f, a2 = 0.f, a3 = 0.f;
    float a4 = 0.f, a5 = 0.f, a6 = 0.f, a7 = 0.f;
    int t = 0;
    for (; t + 8 <= d; t += 8) {
      int s0 = adj[start + t + 0];
      int s1 = adj[start + t + 1];
      int s2 = adj[start + t + 2];
      int s3 = adj[start + t + 3];
      int s4 = adj[start + t + 4];
      int s5 = adj[start + t + 5];
      int s6 = adj[start + t + 6];
      int s7 = adj[start + t + 7];
      a0 += x[(size_t)s0 * DD + j];
      a1 += x[(size_t)s1 * DD + j];
      a2 += x[(size_t)s2 * DD + j];
      a3 += x[(size_t)s3 * DD + j];
      a4 += x[(size_t)s4 * DD + j];
      a5 += x[(size_t)s5 * DD + j];
      a6 += x[(size_t)s6 * DD + j];
      a7 += x[(size_t)s7 * DD + j];
    }
    if (t < d) {                      // uniform masked tail (<=7 rows)
      int dm = d - 1;
      int u1 = (t + 1 < d) ? t + 1 : dm;
      int u2 = (t + 2 < d) ? t + 2 : dm;
      int u3 = (t + 3 < d) ? t + 3 : dm;
      int u4 = (t + 4 < d) ? t + 4 : dm;
      int u5 = (t + 5 < d) ? t + 5 : dm;
      int u6 = (t + 6 < d) ? t + 6 : dm;
      int s0 = adj[start + t];
      int s1 = adj[start + u1];
      int s2 = adj[start + u2];
      int s3 = adj[start + u3];
      int s4 = adj[start + u4];
      int s5 = adj[start + u5];
      int s6 = adj[start + u6];
      float v0 = x[(size_t)s0 * DD + j];
      float v1 = x[(size_t)s1 * DD + j];
      float v2 = x[(size_t)s2 * DD + j];
      float v3 = x[(size_t)s3 * DD + j];
      float v4 = x[(size_t)s4 * DD + j];
      float v5 = x[(size_t)s5 * DD + j];
      float v6 = x[(size_t)s6 * DD + j];
      a0 += v0;
      a1 += (t + 1 < d) ? v1 : 0.f;
      a2 += (t + 2 < d) ? v2 : 0.f;
      a3 += (t + 3 < d) ? v3 : 0.f;
      a4 += (t + 4 < d) ? v4 : 0.f;
      a5 += (t + 5 < d) ? v5 : 0.f;
      a6 += (t + 6 < d) ? v6 : 0.f;
    }
    float sum = ((a0 + a1) + (a2 + a3)) + ((a4 + a5) + (a6 + a7));
    float rc = 1.0f / fmaxf((float)d, 1.0f);
    prop[(size_t)n * DD + j] = sum * rc;
  }
}

// ---------------- dense SAGE GEMM: out = norm(x@wl.T + prop@wr.T + b), relu --
__launch_bounds__(512, 4)
__global__ void sage_gemm_kernel(const float* __restrict__ xin,
                                 const float* __restrict__ prop,
                                 const float* __restrict__ wl,
                                 const float* __restrict__ bl,
                                 const float* __restrict__ wr,
                                 const float* __restrict__ br,
                                 float* __restrict__ out) {
  __shared__ float wlA[DD * DD] __attribute__((aligned(16)));  // [k][j]
  __shared__ float wrA[DD * DD] __attribute__((aligned(16)));  // [k][j]
  __shared__ float sp[8][8][DD] __attribute__((aligned(16)));
  __shared__ float pp[8][8][DD] __attribute__((aligned(16)));
  int tid = threadIdx.x;
  int j = tid & 63;
  int w = tid >> 6;

  for (int i = tid; i < DD * DD; i += 512) {
    int jj = i >> 6, kk = i & 63;
    wlA[kk * DD + jj] = wl[i];
    wrA[kk * DD + jj] = wr[i];
  }
  float bias = bl[j] + br[j];
  __syncthreads();

  const int ngrp = (NOCT + 7) / 8;   // 1563
  for (int grp = blockIdx.x; grp < ngrp; grp += gridDim.x) {
    int o = grp * 8 + w;
    if (o >= NOCT) continue;
    int n0 = o * 8;

    #pragma unroll
    for (int i = 0; i < 8; ++i) {
      sp[w][i][j] = xin[(size_t)(n0 + i) * DD + j];
      pp[w][i][j] = prop[(size_t)(n0 + i) * DD + j];
    }

    float acc[8];
    #pragma unroll
    for (int i = 0; i < 8; ++i) acc[i] = bias;

    #pragma unroll
    for (int q = 0; q < 16; ++q) {
      int kb = q * 4;
      float wl0 = wlA[(kb + 0) * DD + j];
      float wl1 = wlA[(kb + 1) * DD + j];
      float wl2 = wlA[(kb + 2) * DD + j];
      float wl3 = wlA[(kb + 3) * DD + j];
      float wr0 = wrA[(kb + 0) * DD + j];
      float wr1 = wrA[(kb + 1) * DD + j];
      float wr2 = wrA[(kb + 2) * DD + j];
      float wr3 = wrA[(kb + 3) * DD + j];
      #pragma unroll
      for (int i = 0; i < 8; ++i) {
        float4 sv = *(const float4*)&sp[w][i][kb];   // broadcast
        float4 pv = *(const float4*)&pp[w][i][kb];   // broadcast
        float a = acc[i];
        a = fmaf(sv.x, wl0, a);
        a = fmaf(sv.y, wl1, a);
        a = fmaf(sv.z, wl2, a);
        a = fmaf(sv.w, wl3, a);
        a = fmaf(pv.x, wr0, a);
        a = fmaf(pv.y, wr1, a);
        a = fmaf(pv.z, wr2, a);
        a = fmaf(pv.w, wr3, a);
        acc[i] = a;
      }
    }

    #pragma unroll
    for (int i = 0; i < 8; ++i) {
      float a = acc[i];
      float ss = a * a;
      #pragma unroll
      for (int o2 = 32; o2 > 0; o2 >>= 1) ss += __shfl_xor(ss, o2, 64);
      float ov = a / fmaxf(sqrtf(ss), 1e-12f);
      ov = fmaxf(ov, 0.0f);
      out[(size_t)(n0 + i) * DD + j] = ov;
    }
  }
}

// ---------------- combine post weights: wc = w2@w1, bc = w2@b1 + b2 ---------
__global__ void combine_kernel(const float* __restrict__ w1, const float* __restrict__ b1,
                               const float* __restrict__ w2, const float* __restrict__ b2,
                               float* __restrict__ wc, float* __restrict__ bc) {
  int t = threadIdx.x;
  for (int idx = t; idx < DD * DD; idx += 512) {
    int jp = idx >> 6, k = idx & 63;
    float s = 0.f;
    #pragma unroll
    for (int m = 0; m < DD; ++m) s = fmaf(w2[jp * DD + m], w1[m * DD + k], s);
    wc[idx] = s;
  }
  if (t < DD) {
    float s = b2[t];
    #pragma unroll
    for (int m = 0; m < DD; ++m) s = fmaf(w2[t * DD + m], b1[m], s);
    bc[t] = s;
  }
}

// ---------------- post-MLP as a single GEMM (in-place safe) ----------------
__launch_bounds__(512, 4)
__global__ void post_kernel(const float* __restrict__ h,
                            const float* __restrict__ wc,
                            const float* __restrict__ bc,
                            float* __restrict__ out) {
  __shared__ float wA[DD * DD] __attribute__((aligned(16)));   // [k][j]
  __shared__ float hp[8][8][DD] __attribute__((aligned(16)));
  int tid = threadIdx.x;
  int j = tid & 63;
  int w = tid >> 6;

  for (int i = tid; i < DD * DD; i += 512) {
    int jj = i >> 6, kk = i & 63;
    wA[kk * DD + jj] = wc[i];
  }
  float bb = bc[j];
  __syncthreads();

  const int ngrp = (NOCT + 7) / 8;
  for (int grp = blockIdx.x; grp < ngrp; grp += gridDim.x) {
    int o = grp * 8 + w;
    if (o >= NOCT) continue;
    int n0 = o * 8;
    #pragma unroll
    for (int i = 0; i < 8; ++i) hp[w][i][j] = h[(size_t)(n0 + i) * DD + j];

    float acc[8];
    #pragma unroll
    for (int i = 0; i < 8; ++i) acc[i] = bb;
    #pragma unroll
    for (int q = 0; q < 16; ++q) {
      int kb = q * 4;
      float w0 = wA[(kb + 0) * DD + j];
      float w1v = wA[(kb + 1) * DD + j];
      float w2v = wA[(kb + 2) * DD + j];
      float w3v = wA[(kb + 3) * DD + j];
      #pragma unroll
      for (int i = 0; i < 8; ++i) {
        float4 hv = *(const float4*)&hp[w][i][kb];
        float a = acc[i];
        a = fmaf(hv.x, w0, a);
        a = fmaf(hv.y, w1v, a);
        a = fmaf(hv.z, w2v, a);
        a = fmaf(hv.w, w3v, a);
        acc[i] = a;
      }
    }
    #pragma unroll
    for (int i = 0; i < 8; ++i) out[(size_t)(n0 + i) * DD + j] = acc[i];
  }
}

extern "C" void kernel_launch(void* const* d_in, const int* in_sizes, int n_in,
                              void* d_out, int out_size, void* d_ws, size_t ws_size,
                              hipStream_t stream) {
  const float* x   = (const float*)d_in[0];
  const int*   ei  = (const int*)d_in[1];
  const float* w1l = (const float*)d_in[2];
  const float* b1l = (const float*)d_in[3];
  const float* w1r = (const float*)d_in[4];
  const float* b1r = (const float*)d_in[5];
  const float* w2l = (const float*)d_in[6];
  const float* b2l = (const float*)d_in[7];
  const float* w2r = (const float*)d_in[8];
  const float* b2r = (const float*)d_in[9];
  const float* wp1 = (const float*)d_in[10];
  const float* bp1 = (const float*)d_in[11];
  const float* wp2 = (const float*)d_in[12];
  const float* bp2 = (const float*)d_in[13];
  float* out = (float*)d_out;

  const int* src = ei;
  const int* dst = ei + NE;

  // ws (4B units): degc[102400] | off[102400] | bsum[1024] | wc[4096] | bc[1024]
  //               | adj[NE] | prop[NN*DD]
  // Aliased into prop (both dead before gather writes prop):
  //   rank = prop[0 .. NE)            (needed until fill)
  //   degp = prop[NE .. NE+NN*PAD)    (needed until scan1)
  int* degc  = (int*)d_ws;
  int* off   = degc + 102400;
  int* bsum  = off + 102400;
  float* wc  = (float*)(bsum + 1024);
  float* bc  = wc + 4096;
  int* adj   = (int*)(bc + 1024);
  float* prop = (float*)(adj + NE);
  int* rank  = (int*)prop;                 // [NE]
  int* degp  = rank + NE;                  // [NN*PAD] padded counters

  const int e4grid = (NE / 4 + 255) / 256;   // 1563

  // ---- build CSR once ----
  zero_kernel<<<2048, 256, 0, stream>>>(degp, NN * PAD);
  hist_kernel<<<NBLK, 256, 0, stream>>>(dst, degp, rank);
  scan1_kernel<<<NBLK, SCAN_BS, 0, stream>>>(degp, degc, off, bsum);
  scan2_kernel<<<1, 512, 0, stream>>>(bsum);
  scan3_kernel<<<NBLK, SCAN_BS, 0, stream>>>(off, bsum);
  fill_kernel<<<e4grid, 256, 0, stream>>>(src, dst, off, rank, adj);
  combine_kernel<<<1, 512, 0, stream>>>(wp1, bp1, wp2, bp2, wc, bc);

  // ---- layer 1: gather(x)->prop; gemm(x,prop)->out ----
  gather_kernel<<<2048, 256, 0, stream>>>(x, off, degc, adj, prop);
  sage_gemm_kernel<<<512, 512, 0, stream>>>(x, prop, w1l, b1l, w1r, b1r, out);

  // ---- layer 2: gather(out)->prop; gemm(out,prop)->out (in-place safe) ----
  gather_kernel<<<2048, 256, 0, stream>>>(out, off, degc, adj, prop);
  sage_gemm_kernel<<<512, 512, 0, stream>>>(out, prop, w2l, b2l, w2r, b2r, out);

  // ---- post-MLP (single combined GEMM, in-place) ----
  post_kernel<<<512, 512, 0, stream>>>(out, wc, bc, out);
}